// Round 5
// baseline (211.072 us; speedup 1.0000x reference)
//
#include <hip/hip_runtime.h>
#include <hip/hip_bf16.h>

#define BATCH 32
#define LSEQ  512
#define NDIM  1024
#define NSPLIT 16

typedef __attribute__((ext_vector_type(8))) short bf16x8;
typedef __attribute__((ext_vector_type(4))) float f32x4;

__device__ __forceinline__ unsigned short f2bf(float x) {
    __hip_bfloat16 h = __float2bfloat16(x);
    return __builtin_bit_cast(unsigned short, h);
}

__device__ __forceinline__ void glds16(const unsigned short* g, unsigned short* l) {
    __builtin_amdgcn_global_load_lds(
        (const __attribute__((address_space(1))) void*)g,
        (__attribute__((address_space(3))) void*)l, 16, 0, 0);
}

// ---------------------------------------------------------------------------
// Kernel 1: fused X fp32 -> bf16 conversion + s1/s2 partial sums
// grid (NSPLIT l-splits, 32 batches) x 256 threads; thread t owns n = 4t..4t+3
// ---------------------------------------------------------------------------
__global__ __launch_bounds__(256) void prep_kernel(
    const float* __restrict__ X, const float* __restrict__ W,
    unsigned short* __restrict__ Xb, float* __restrict__ P1, float* __restrict__ P2)
{
    __shared__ float sw[2 * LSEQ];
    int tid = threadIdx.x;
    for (int i = tid; i < 2 * LSEQ; i += 256) sw[i] = W[i];
    __syncthreads();

    int b  = blockIdx.y;
    int sp = blockIdx.x;
    int l0 = sp * (LSEQ / NSPLIT);
    size_t base = ((size_t)b * LSEQ + l0) * NDIM + tid * 4;
    const float* xp = X + base;
    unsigned short* xbp = Xb + base;

    float a0=0,a1=0,a2=0,a3=0, c0=0,c1=0,c2=0,c3=0;
    for (int l = 0; l < LSEQ / NSPLIT; ++l) {
        float4 x = *(const float4*)(xp + (size_t)l * NDIM);
        float w1 = sw[l0 + l], w2 = sw[LSEQ + l0 + l];
        a0 = fmaf(x.x, w1, a0); a1 = fmaf(x.y, w1, a1);
        a2 = fmaf(x.z, w1, a2); a3 = fmaf(x.w, w1, a3);
        c0 = fmaf(x.x, w2, c0); c1 = fmaf(x.y, w2, c1);
        c2 = fmaf(x.z, w2, c2); c3 = fmaf(x.w, w2, c3);
        ushort4 u; u.x = f2bf(x.x); u.y = f2bf(x.y); u.z = f2bf(x.z); u.w = f2bf(x.w);
        *(ushort4*)(xbp + (size_t)l * NDIM) = u;
    }
    size_t po = ((size_t)sp * BATCH + b) * NDIM + tid * 4;
    *(float4*)(P1 + po) = make_float4(a0, a1, a2, a3);
    *(float4*)(P2 + po) = make_float4(c0, c1, c2, c3);
}

// ---------------------------------------------------------------------------
// Kernel 2: fused reduce + softmax stats + Bt generation.
// Grid 256 = (b:32) x (jslice:8, 128 j each).
// Phase A: reduce s1[b,:] (LDS) and s2 slice.  Phase B: rd[j] = 1/sum_i exp(e)
// (no max-sub; e bounded, validated R3/R4).  Phase C: write
// Bt[b][i][j0..j0+127] = bf16(exp(e_ij) * rd_j)  (GEMM B-operand [n=i][k=j]).
// ---------------------------------------------------------------------------
__global__ __launch_bounds__(256) void statsbt_kernel(
    const float* __restrict__ P1, const float* __restrict__ P2,
    unsigned short* __restrict__ Bt)
{
    __shared__ float s1s[NDIM];
    __shared__ float s2s[128];
    __shared__ float rds[128];
    int t = threadIdx.x;
    int b = blockIdx.x >> 3, sl = blockIdx.x & 7;
    int j0 = sl * 128;

    // Phase A: reductions
    #pragma unroll
    for (int q = 0; q < 4; ++q) {
        int n = q * 256 + t;
        float a = 0.f;
        #pragma unroll
        for (int sp = 0; sp < NSPLIT; ++sp)
            a += P1[((size_t)sp * BATCH + b) * NDIM + n];
        s1s[n] = a;
    }
    if (t < 128) {
        int j = j0 + t;
        float c = 0.f;
        #pragma unroll
        for (int sp = 0; sp < NSPLIT; ++sp)
            c += P2[((size_t)sp * BATCH + b) * NDIM + j];
        s2s[t] = c;
    }
    __syncthreads();

    // Phase B: denominators (thread pair per j; halves of i-range)
    {
        int jl = t >> 1, half = t & 1;
        int jg = j0 + jl;
        float s2j = s2s[jl];
        float sum = 0.f;
        int i0 = half * 512;
        for (int i = i0; i < i0 + 512; ++i) {
            float v = s1s[i] + s2j;
            v = fmaxf(v, 0.01f * v);       // leaky relu
            if (i == jg) v = 0.f;          // diag of e zeroed before softmax
            sum += __expf(v);
        }
        sum += __shfl_xor(sum, 1);
        if (half == 0) rds[jl] = 1.0f / sum;
    }
    __syncthreads();

    // Phase C: emit Bt slice. thread t -> 4 j's (t&31)*4, i-stream t>>5 step 8
    int jq = (t & 31) * 4;
    int ir = t >> 5;
    float4 s2v = *(const float4*)&s2s[jq];
    float4 rdv = *(const float4*)&rds[jq];
    unsigned short* outp = Bt + (size_t)b * NDIM * NDIM + j0 + jq;
    for (int i = ir; i < NDIM; i += 8) {
        float s1i = s1s[i];
        float e0 = s1i + s2v.x, e1 = s1i + s2v.y, e2 = s1i + s2v.z, e3 = s1i + s2v.w;
        e0 = fmaxf(e0, 0.01f*e0); e1 = fmaxf(e1, 0.01f*e1);
        e2 = fmaxf(e2, 0.01f*e2); e3 = fmaxf(e3, 0.01f*e3);
        int jg = j0 + jq;
        if (jg + 0 == i) e0 = 0.f;
        if (jg + 1 == i) e1 = 0.f;
        if (jg + 2 == i) e2 = 0.f;
        if (jg + 3 == i) e3 = 0.f;
        ushort4 u;
        u.x = f2bf(__expf(e0) * rdv.x);
        u.y = f2bf(__expf(e1) * rdv.y);
        u.z = f2bf(__expf(e2) * rdv.z);
        u.w = f2bf(__expf(e3) * rdv.w);
        *(ushort4*)(outp + (size_t)i * NDIM) = u;
    }
}

// ---------------------------------------------------------------------------
// Kernel 3: batched GEMM  out[b] = sigmoid( Xb[b] (512x1024) @ Bt[b]^T )
// 128x128 tile, BK=32, TRUE double-buffered async pipeline:
//   issue loads(k+1) -> idle buf;  s_waitcnt vmcnt(4) (waits only loads(k),
//   issued a full iteration ago);  raw s_barrier;  compute(k);  raw s_barrier.
// The prefetch is never drained by the barrier (unlike __syncthreads' vmcnt(0)).
// XCD swizzle: xcd = flat&7 processes one batch at a time (L2-resident).
// ---------------------------------------------------------------------------
__global__ __launch_bounds__(256) void gemm_kernel(
    const unsigned short* __restrict__ Xb, const unsigned short* __restrict__ Bt,
    float* __restrict__ out)
{
    __shared__ __align__(16) unsigned short Xs[2][128 * 32];
    __shared__ __align__(16) unsigned short Bs[2][128 * 32];

    int tid = threadIdx.x, wid = tid >> 6, lane = tid & 63;
    int wm = wid >> 1, wn = wid & 1;

    int flat = blockIdx.x;
    int xcd   = flat & 7;
    int idx   = flat >> 3;
    int bg    = idx >> 5;
    int inner = idx & 31;
    int b  = bg * 8 + xcd;
    int n0 = (inner & 7) * 128;
    int l0 = (inner >> 3) * 128;

    const unsigned short* Xg = Xb + ((size_t)b * LSEQ + l0) * NDIM;
    const unsigned short* Bg = Bt + ((size_t)b * NDIM + n0) * NDIM;

    int rin = lane >> 2, ch = lane & 3;    // staging: 4 lanes per 64B row
    int srow0 = wid * 32, srow1 = wid * 32 + 16;

    // prologue: stage tile 0 into buffer 0 (4 loads/wave)
    glds16(Xg + (size_t)(srow0 + rin) * NDIM + ch * 8, &Xs[0][srow0 * 32]);
    glds16(Bg + (size_t)(srow0 + rin) * NDIM + ch * 8, &Bs[0][srow0 * 32]);
    glds16(Xg + (size_t)(srow1 + rin) * NDIM + ch * 8, &Xs[0][srow1 * 32]);
    glds16(Bg + (size_t)(srow1 + rin) * NDIM + ch * 8, &Bs[0][srow1 * 32]);

    f32x4 acc[4][4] = {};
    int rsel = lane & 15, ksel = (lane >> 4) * 8;

    for (int kb = 0; kb < 32; ++kb) {
        int cur = kb & 1;
        int nxt = cur ^ 1;
        int knext = ((kb + 1) & 31) * 32;  // kb=31 wraps: harmless redundant load

        // issue prefetch for tile kb+1 into idle buffer (4 loads/wave)
        glds16(Xg + (size_t)(srow0 + rin) * NDIM + knext + ch * 8, &Xs[nxt][srow0 * 32]);
        glds16(Bg + (size_t)(srow0 + rin) * NDIM + knext + ch * 8, &Bs[nxt][srow0 * 32]);
        glds16(Xg + (size_t)(srow1 + rin) * NDIM + knext + ch * 8, &Xs[nxt][srow1 * 32]);
        glds16(Bg + (size_t)(srow1 + rin) * NDIM + knext + ch * 8, &Bs[nxt][srow1 * 32]);

        // wait ONLY the 4 loads of tile kb (issued one full iteration ago),
        // then sync waves withOUT draining the prefetch.
        asm volatile("s_waitcnt vmcnt(4)\n\ts_barrier" ::: "memory");

        bf16x8 av[4], bv[4];
        #pragma unroll
        for (int mi = 0; mi < 4; ++mi)
            av[mi] = *(const bf16x8*)&Xs[cur][(wm * 64 + mi * 16 + rsel) * 32 + ksel];
        #pragma unroll
        for (int ni = 0; ni < 4; ++ni)
            bv[ni] = *(const bf16x8*)&Bs[cur][(wn * 64 + ni * 16 + rsel) * 32 + ksel];
        #pragma unroll
        for (int mi = 0; mi < 4; ++mi)
            #pragma unroll
            for (int ni = 0; ni < 4; ++ni)
                acc[mi][ni] = __builtin_amdgcn_mfma_f32_16x16x32_bf16(
                    av[mi], bv[ni], acc[mi][ni], 0, 0, 0);

        // all waves done reading buf[cur] before it's overwritten next iter
        asm volatile("s_barrier" ::: "memory");
    }

    // epilogue: C/D layout col=lane&15, row=(lane>>4)*4+reg  [m89/m91 verified]
    float* outb = out + ((size_t)b * LSEQ + l0) * NDIM + n0;
    int rq = lane >> 4, cl = lane & 15;
    #pragma unroll
    for (int mi = 0; mi < 4; ++mi)
        #pragma unroll
        for (int ni = 0; ni < 4; ++ni) {
            int col = wn * 64 + ni * 16 + cl;
            #pragma unroll
            for (int r2 = 0; r2 < 4; ++r2) {
                int row = wm * 64 + mi * 16 + rq * 4 + r2;
                float v = acc[mi][ni][r2];
                outb[(size_t)row * NDIM + col] = 1.0f / (1.0f + __expf(-v));
            }
        }
}

// ---------------------------------------------------------------------------
extern "C" void kernel_launch(void* const* d_in, const int* in_sizes, int n_in,
                              void* d_out, int out_size, void* d_ws, size_t ws_size,
                              hipStream_t stream) {
    (void)in_sizes; (void)n_in; (void)out_size; (void)ws_size;
    const float* X = (const float*)d_in[0];
    const float* W = (const float*)d_in[1];
    float* out = (float*)d_out;

    // workspace: P1|P2 (512K floats each) | Xb bf16 32MB | Bt bf16 64MB
    float* P1 = (float*)d_ws;
    float* P2 = P1 + (size_t)NSPLIT * BATCH * NDIM;
    unsigned short* Xb = (unsigned short*)(P2 + (size_t)NSPLIT * BATCH * NDIM);
    unsigned short* Bt = Xb + (size_t)BATCH * LSEQ * NDIM;

    prep_kernel<<<dim3(NSPLIT, BATCH), 256, 0, stream>>>(X, W, Xb, P1, P2);
    statsbt_kernel<<<256, 256, 0, stream>>>(P1, P2, Bt);
    gemm_kernel<<<1024, 256, 0, stream>>>(Xb, Bt, out);
}

// Round 6
// 202.250 us; speedup vs baseline: 1.0436x; 1.0436x over previous
//
#include <hip/hip_runtime.h>
#include <hip/hip_bf16.h>

#define BATCH 32
#define LSEQ  512
#define NDIM  1024
#define NSPLIT 16

typedef __attribute__((ext_vector_type(8))) short bf16x8;
typedef __attribute__((ext_vector_type(4))) float f32x4;

__device__ __forceinline__ unsigned short f2bf(float x) {
    __hip_bfloat16 h = __float2bfloat16(x);
    return __builtin_bit_cast(unsigned short, h);
}

__device__ __forceinline__ void glds16(const unsigned short* g, unsigned short* l) {
    __builtin_amdgcn_global_load_lds(
        (const __attribute__((address_space(1))) void*)g,
        (__attribute__((address_space(3))) void*)l, 16, 0, 0);
}

// ---------------------------------------------------------------------------
// Kernel 1: fused X fp32 -> bf16 conversion + s1/s2 partial sums
// grid (NSPLIT l-splits, 32 batches) x 256 threads; thread t owns n = 4t..4t+3
// ---------------------------------------------------------------------------
__global__ __launch_bounds__(256) void prep_kernel(
    const float* __restrict__ X, const float* __restrict__ W,
    unsigned short* __restrict__ Xb, float* __restrict__ P1, float* __restrict__ P2)
{
    __shared__ float sw[2 * LSEQ];
    int tid = threadIdx.x;
    for (int i = tid; i < 2 * LSEQ; i += 256) sw[i] = W[i];
    __syncthreads();

    int b  = blockIdx.y;
    int sp = blockIdx.x;
    int l0 = sp * (LSEQ / NSPLIT);
    size_t base = ((size_t)b * LSEQ + l0) * NDIM + tid * 4;
    const float* xp = X + base;
    unsigned short* xbp = Xb + base;

    float a0=0,a1=0,a2=0,a3=0, c0=0,c1=0,c2=0,c3=0;
    for (int l = 0; l < LSEQ / NSPLIT; ++l) {
        float4 x = *(const float4*)(xp + (size_t)l * NDIM);
        float w1 = sw[l0 + l], w2 = sw[LSEQ + l0 + l];
        a0 = fmaf(x.x, w1, a0); a1 = fmaf(x.y, w1, a1);
        a2 = fmaf(x.z, w1, a2); a3 = fmaf(x.w, w1, a3);
        c0 = fmaf(x.x, w2, c0); c1 = fmaf(x.y, w2, c1);
        c2 = fmaf(x.z, w2, c2); c3 = fmaf(x.w, w2, c3);
        ushort4 u; u.x = f2bf(x.x); u.y = f2bf(x.y); u.z = f2bf(x.z); u.w = f2bf(x.w);
        *(ushort4*)(xbp + (size_t)l * NDIM) = u;
    }
    size_t po = ((size_t)sp * BATCH + b) * NDIM + tid * 4;
    *(float4*)(P1 + po) = make_float4(a0, a1, a2, a3);
    *(float4*)(P2 + po) = make_float4(c0, c1, c2, c3);
}

// ---------------------------------------------------------------------------
// Kernel 2: fused reduce + softmax-denominator stats (no max-subtraction;
// e = lrelu(s1+s2) is bounded, fp32 exp safe — validated R3/R4).
// Grid 256 = (b:32) x (jslice:8, 128 j each).
// ---------------------------------------------------------------------------
__global__ __launch_bounds__(256) void stats_kernel(
    const float* __restrict__ P1, const float* __restrict__ P2,
    float* __restrict__ s1, float* __restrict__ s2, float* __restrict__ rd)
{
    __shared__ float s1s[NDIM];
    __shared__ float s2s[128];
    int t = threadIdx.x;
    int b = blockIdx.x >> 3, sl = blockIdx.x & 7;
    int j0 = sl * 128;

    #pragma unroll
    for (int q = 0; q < 4; ++q) {
        int n = q * 256 + t;
        float a = 0.f;
        #pragma unroll
        for (int sp = 0; sp < NSPLIT; ++sp)
            a += P1[((size_t)sp * BATCH + b) * NDIM + n];
        s1s[n] = a;
        if (sl == 0) s1[b * NDIM + n] = a;
    }
    if (t < 128) {
        int j = j0 + t;
        float c = 0.f;
        #pragma unroll
        for (int sp = 0; sp < NSPLIT; ++sp)
            c += P2[((size_t)sp * BATCH + b) * NDIM + j];
        s2s[t] = c;
        s2[b * NDIM + j] = c;
    }
    __syncthreads();

    int jl = t >> 1, half = t & 1;
    int jg = j0 + jl;
    float s2j = s2s[jl];
    float sum = 0.f;
    int i0 = half * 512;
    for (int i = i0; i < i0 + 512; ++i) {
        float v = s1s[i] + s2j;
        v = fmaxf(v, 0.01f * v);          // leaky relu
        if (i == jg) v = 0.f;             // diag of e zeroed before softmax
        sum += __expf(v);
    }
    sum += __shfl_xor(sum, 1);
    if (half == 0) rd[b * NDIM + jg] = 1.0f / sum;
}

// ---------------------------------------------------------------------------
// Kernel 3: Bt[b][i][j] = exp(e_ij) * rd[b,j] in bf16 (GEMM B-operand [n][k]).
// One wave per (b,i); lane owns 8 contiguous j per pass, 2 passes; 16B stores.
// ---------------------------------------------------------------------------
__global__ __launch_bounds__(256) void btgen_kernel(
    const float* __restrict__ s1, const float* __restrict__ s2,
    const float* __restrict__ rd, unsigned short* __restrict__ Bt)
{
    int wid = threadIdx.x >> 6, lane = threadIdx.x & 63;
    int r = blockIdx.x * 4 + wid;          // (b,i) flat
    int b = r >> 10, i = r & 1023;
    float s1i = s1[r];
    const float* s2b = s2 + b * NDIM;
    const float* rdb = rd + b * NDIM;
    unsigned short* outp = Bt + (size_t)r * NDIM;

    #pragma unroll
    for (int q = 0; q < 2; ++q) {
        int j0 = q * 512 + lane * 8;
        float sv[8], rv[8];
        #pragma unroll
        for (int h = 0; h < 2; ++h) {
            float4 s4 = *(const float4*)(s2b + j0 + h * 4);
            float4 r4 = *(const float4*)(rdb + j0 + h * 4);
            sv[h*4+0]=s4.x; sv[h*4+1]=s4.y; sv[h*4+2]=s4.z; sv[h*4+3]=s4.w;
            rv[h*4+0]=r4.x; rv[h*4+1]=r4.y; rv[h*4+2]=r4.z; rv[h*4+3]=r4.w;
        }
        bf16x8 v;
        #pragma unroll
        for (int k = 0; k < 8; ++k) {
            float e = s1i + sv[k];
            e = fmaxf(e, 0.01f * e);       // leaky relu
            if (j0 + k == i) e = 0.f;      // diag of e zeroed (alpha nonzero there)
            v[k] = (short)f2bf(__expf(e) * rv[k]);
        }
        *(bf16x8*)&outp[j0] = v;
    }
}

// ---------------------------------------------------------------------------
// Kernel 4: batched GEMM  out[b] = sigmoid( Xb[b] (512x1024) @ Bt[b]^T )
// 128x128 tile, BK=64 as two k-halves [kh][128][32], 16 K-iters, 4 waves
// (2x2), 16x16x32 bf16 MFMA. NEW: epilogue transposes each wave's 16x64
// slice through LDS (row stride 68 -> only 2-way bank aliasing, free) so
// stores are coalesced global_store_dwordx4 instead of 64 scattered dwords.
// XCD swizzle: xcd = flat&7 processes one batch at a time (L2-resident).
// ---------------------------------------------------------------------------
__global__ __launch_bounds__(256) void gemm_kernel(
    const unsigned short* __restrict__ Xb, const unsigned short* __restrict__ Bt,
    float* __restrict__ out)
{
    __shared__ __align__(16) unsigned short Xs[2 * 128 * 32];  // [kh][row][32]
    __shared__ __align__(16) unsigned short Bs[2 * 128 * 32];

    int tid = threadIdx.x, wid = tid >> 6, lane = tid & 63;
    int wm = wid >> 1, wn = wid & 1;

    int flat = blockIdx.x;
    int xcd   = flat & 7;
    int idx   = flat >> 3;
    int bg    = idx >> 5;
    int inner = idx & 31;
    int b  = bg * 8 + xcd;
    int n0 = (inner & 7) * 128;
    int l0 = (inner >> 3) * 128;

    const unsigned short* Xg = Xb + ((size_t)b * LSEQ + l0) * NDIM;
    const unsigned short* Bg = Bt + ((size_t)b * NDIM + n0) * NDIM;

    int rin = lane >> 2, ch = lane & 3;    // staging: 4 lanes per 64B row-half

    f32x4 acc[4][4] = {};

    for (int kb = 0; kb < 16; ++kb) {
        int k0 = kb * 64;
        __syncthreads();                   // protect LDS from prior-iter readers
        #pragma unroll
        for (int kh = 0; kh < 2; ++kh) {
            #pragma unroll
            for (int q = 0; q < 2; ++q) {
                int row = wid * 32 + q * 16 + rin;
                int kg = k0 + kh * 32 + ch * 8;
                const unsigned short* gx = Xg + (size_t)row * NDIM + kg;
                const unsigned short* gb = Bg + (size_t)row * NDIM + kg;
                unsigned short* lx = &Xs[kh * 4096 + (wid * 32 + q * 16) * 32];
                unsigned short* lb = &Bs[kh * 4096 + (wid * 32 + q * 16) * 32];
                glds16(gx, lx);
                glds16(gb, lb);
            }
        }
        __syncthreads();

        int rsel = lane & 15, ksel = (lane >> 4) * 8;
        #pragma unroll
        for (int kh = 0; kh < 2; ++kh) {
            bf16x8 av[4], bv[4];
            #pragma unroll
            for (int mi = 0; mi < 4; ++mi)
                av[mi] = *(const bf16x8*)&Xs[kh * 4096 + (wm * 64 + mi * 16 + rsel) * 32 + ksel];
            #pragma unroll
            for (int ni = 0; ni < 4; ++ni)
                bv[ni] = *(const bf16x8*)&Bs[kh * 4096 + (wn * 64 + ni * 16 + rsel) * 32 + ksel];
            #pragma unroll
            for (int mi = 0; mi < 4; ++mi)
                #pragma unroll
                for (int ni = 0; ni < 4; ++ni)
                    acc[mi][ni] = __builtin_amdgcn_mfma_f32_16x16x32_bf16(
                        av[mi], bv[ni], acc[mi][ni], 0, 0, 0);
        }
    }

    // ---- transposed epilogue ----
    // C/D layout: col=lane&15, row=(lane>>4)*4+reg [m89/m91 verified].
    // Each wave round-trips its 16x64 (rows x cols) mi-slice through LDS
    // (fp32, row stride 68: 272 B -> 16B-aligned rows, 2-way banks only),
    // reads back row-major float4, applies sigmoid, stores dwordx4.
    __syncthreads();                       // all waves done reading Xs/Bs
    float* scr = ((wid & 2) ? (float*)Bs : (float*)Xs) + (wid & 1) * 1088;
    float* outb = out + ((size_t)b * LSEQ + l0) * NDIM + n0;
    int rq = lane >> 4, cl = lane & 15;
    #pragma unroll
    for (int mi = 0; mi < 4; ++mi) {
        #pragma unroll
        for (int ni = 0; ni < 4; ++ni)
            #pragma unroll
            for (int r2 = 0; r2 < 4; ++r2)
                scr[(rq * 4 + r2) * 68 + ni * 16 + cl] = acc[mi][ni][r2];
        // wave-internal LDS dependency: compiler inserts lgkmcnt wait
        #pragma unroll
        for (int p = 0; p < 4; ++p) {
            int row = p * 4 + (lane >> 4);       // 0..15 within slice
            int col = (lane & 15) * 4;           // 0..60, float4
            float4 v = *(const float4*)&scr[row * 68 + col];
            v.x = 1.0f / (1.0f + __expf(-v.x));
            v.y = 1.0f / (1.0f + __expf(-v.y));
            v.z = 1.0f / (1.0f + __expf(-v.z));
            v.w = 1.0f / (1.0f + __expf(-v.w));
            int grow = wm * 64 + mi * 16 + row;
            int gcol = wn * 64 + col;
            *(float4*)&outb[(size_t)grow * NDIM + gcol] = v;
        }
    }
}

// ---------------------------------------------------------------------------
extern "C" void kernel_launch(void* const* d_in, const int* in_sizes, int n_in,
                              void* d_out, int out_size, void* d_ws, size_t ws_size,
                              hipStream_t stream) {
    (void)in_sizes; (void)n_in; (void)out_size; (void)ws_size;
    const float* X = (const float*)d_in[0];
    const float* W = (const float*)d_in[1];
    float* out = (float*)d_out;

    // workspace: s1|s2|rd (32K floats each) | P1|P2 (512K floats each)
    //            | Xb bf16 32MB | Bt bf16 64MB
    float* s1 = (float*)d_ws;
    float* s2 = s1 + BATCH * NDIM;
    float* rd = s2 + BATCH * NDIM;
    float* P1 = rd + BATCH * NDIM;
    float* P2 = P1 + (size_t)NSPLIT * BATCH * NDIM;
    unsigned short* Xb = (unsigned short*)(P2 + (size_t)NSPLIT * BATCH * NDIM);
    unsigned short* Bt = Xb + (size_t)BATCH * LSEQ * NDIM;

    prep_kernel<<<dim3(NSPLIT, BATCH), 256, 0, stream>>>(X, W, Xb, P1, P2);
    stats_kernel<<<256, 256, 0, stream>>>(P1, P2, s1, s2, rd);
    btgen_kernel<<<(BATCH * NDIM) / 4, 256, 0, stream>>>(s1, s2, rd, Bt);
    gemm_kernel<<<1024, 256, 0, stream>>>(Xb, Bt, out);
}